// Round 1
// baseline (16746.431 us; speedup 1.0000x reference)
//
#include <hip/hip_runtime.h>
#include <math.h>
#include <stdint.h>
#include <stddef.h>

// TreeEnergyLoss on gfx950 — fully on-device MST + tree-filter DP.
//
// Key correctness invariants:
//  * MST must match host Kruskal on float64 weights with stable-sort tie-break
//    => Boruvka under total order (double weight bits, edge index).
//  * Tree filter is orientation independent => any root works; we use node 0.
//  * Up-pass sibling conflicts handled with float atomicAdd (== scatter-add).

namespace {
constexpr int Bn  = 4, Cc = 21, Hh = 96, Ww = 96;
constexpr int Nn  = Hh * Ww;              // 9216 nodes
constexpr int EhE = Hh * (Ww - 1);        // 9120 horizontal edges
constexpr int Ne  = EhE + (Hh - 1) * Ww;  // 18240 edges
constexpr int Clow = 3, Chigh = 512;
constexpr int NTH = 1024;

// workspace layout (bytes)
constexpr size_t OFF_ACC  = 0;                                      // 2 doubles: loss, count
constexpr size_t OFF_PROB = 256;                                    // float[B][21][Nn]
constexpr size_t OFF_A    = OFF_PROB + (size_t)Bn * Cc * Nn * 4;    // float[B][22][Nn]
constexpr size_t OFF_EWL  = OFF_A + (size_t)Bn * (Cc + 1) * Nn * 4; // double[B][Ne]
constexpr size_t OFF_EWH  = OFF_EWL + (size_t)Bn * Ne * 8;          // double[B][Ne]
constexpr size_t OFF_SCR  = OFF_EWH + (size_t)Bn * Ne * 8;          // per-batch scratch

// per-batch scratch offsets
constexpr size_t SO_CBW  = 0;                                  // ull[Nn]  best weight bits per comp
constexpr size_t SO_UF   = SO_CBW + (size_t)Nn * 8;            // int[Nn]  union-find
constexpr size_t SO_CBE  = SO_UF  + (size_t)Nn * 4;            // int[Nn]  best edge per comp
constexpr size_t SO_NXT  = SO_CBE + (size_t)Nn * 4;            // int[Nn]  star-contraction ptr
constexpr size_t SO_DEG  = SO_NXT + (size_t)Nn * 4;            // int[Nn]  tree degree
constexpr size_t SO_PAR  = SO_DEG + (size_t)Nn * 4;            // int[Nn]  comp-cache, then BFS parent
constexpr size_t SO_ORD  = SO_PAR + (size_t)Nn * 4;            // int[Nn]  BFS order
constexpr size_t SO_WGT  = SO_ORD + (size_t)Nn * 4;            // float[Nn] filter edge weight to parent
constexpr size_t SO_LEV  = SO_WGT + (size_t)Nn * 4;            // int[Nn+2] level offsets
constexpr size_t SO_MSTF = SO_LEV + (size_t)(Nn + 2) * 4;      // int[Ne]  edge-in-MST flag
constexpr size_t SO_ADJN = SO_MSTF + (size_t)Ne * 4;           // int[Nn][4] tree neighbors
constexpr size_t SO_ADJE = SO_ADJN + (size_t)Nn * 16;          // int[Nn][4] tree edge ids
constexpr size_t SCR_PER_B = SO_ADJE + (size_t)Nn * 16;        // 736,520 B per batch
} // namespace

// edge id -> endpoints, matching reference concatenate([eh, ev]) ordering
__device__ __forceinline__ void edge_nodes(int e, int& a, int& b) {
    if (e < EhE) {                    // horizontal: h in [0,96), w in [0,95)
        int h = e / (Ww - 1), w = e - h * (Ww - 1);
        a = h * Ww + w; b = a + 1;
    } else {                          // vertical: h in [0,95), w in [0,96)
        int e2 = e - EhE;
        int h = e2 / Ww, w = e2 - h * Ww;
        a = h * Ww + w; b = a + Ww;
    }
}

__device__ __forceinline__ int uf_find(int* uf, int x) {
    while (true) {
        int p = uf[x];
        if (p == x) return x;
        int gp = uf[p];
        if (gp != p) uf[x] = gp;  // path halving (benign races)
        x = gp;
    }
}

__global__ void k_init(const float* __restrict__ preds, float* __restrict__ prob,
                       float* __restrict__ A, double* __restrict__ acc) {
    int idx = blockIdx.x * blockDim.x + threadIdx.x;
    if (idx == 0) { acc[0] = 0.0; acc[1] = 0.0; }
    int total = Bn * (Cc + 1) * Nn;
    if (idx >= total) return;
    int b = idx / ((Cc + 1) * Nn);
    int rem = idx - b * ((Cc + 1) * Nn);
    int c = rem / Nn, n = rem - c * Nn;
    if (c < Cc) {
        float x = preds[((size_t)b * Cc + c) * Nn + n];
        float p = 1.0f / (1.0f + expf(-x));
        prob[((size_t)b * Cc + c) * Nn + n] = p;
        A[idx] = p;
    } else {
        A[idx] = 1.0f;   // norm channel
    }
}

// exact float64 edge weights: sequential channel sum matches numpy axis-0 reduce
__global__ void k_edgew(const float* __restrict__ feat, int C, double* __restrict__ ew) {
    int idx = blockIdx.x * blockDim.x + threadIdx.x;
    if (idx >= Bn * Ne) return;
    int b = idx / Ne, e = idx - b * Ne;
    int a, c2; edge_nodes(e, a, c2);
    const float* f = feat + (size_t)b * C * Nn;
    double s = 0.0;
    for (int c = 0; c < C; c++) {
        double d = (double)f[(size_t)c * Nn + a] - (double)f[(size_t)c * Nn + c2];
        s += d * d;
    }
    ew[idx] = s;
}

// One block per batch: Boruvka MST -> BFS from node 0 -> two-pass tree DP.
// mode 0: epilogue normalizes A in place (input for second filter)
// mode 1: epilogue accumulates loss and roi count into acc[0], acc[1]
__global__ void __launch_bounds__(NTH)
k_tree(char* __restrict__ ws, const double* __restrict__ ewAll, float sigma, int mode,
       const float* __restrict__ roi) {
    const int b = blockIdx.x, tid = threadIdx.x;
    char* sb = ws + OFF_SCR + (size_t)b * SCR_PER_B;
    unsigned long long* cbW = (unsigned long long*)(sb + SO_CBW);
    int*   uf   = (int*)(sb + SO_UF);
    int*   cbE  = (int*)(sb + SO_CBE);
    int*   nxt  = (int*)(sb + SO_NXT);
    int*   deg  = (int*)(sb + SO_DEG);
    int*   par  = (int*)(sb + SO_PAR);   // comp cache during Boruvka, BFS parent after
    int*   ord  = (int*)(sb + SO_ORD);
    float* wgt  = (float*)(sb + SO_WGT);
    int*   lev  = (int*)(sb + SO_LEV);
    int*   mstf = (int*)(sb + SO_MSTF);
    int*   adjN = (int*)(sb + SO_ADJN);
    int*   adjE = (int*)(sb + SO_ADJE);
    const double* ew = ewAll + (size_t)b * Ne;
    float* A = (float*)(ws + OFF_A) + (size_t)b * (Cc + 1) * Nn;
    const float* prob = (const float*)(ws + OFF_PROB);
    double* acc = (double*)(ws + OFF_ACC);

    __shared__ int sMst, sNxt, sChg;

    // ---- init ----
    if (tid == 0) sMst = 0;
    for (int i = tid; i < Nn; i += NTH) { uf[i] = i; deg[i] = 0; }
    for (int e = tid; e < Ne; e += NTH) mstf[e] = 0;
    __syncthreads();

    // ---- Boruvka under total order (double weight bits, edge index) ----
    for (int round = 0; round < 24; round++) {
        if (sMst >= Nn - 1) break;
        for (int i = tid; i < Nn; i += NTH) { cbW[i] = ~0ull; cbE[i] = 0x7fffffff; }
        __syncthreads();
        for (int i = tid; i < Nn; i += NTH) par[i] = uf_find(uf, i);  // comp snapshot
        __syncthreads();
        // pass 1: min weight per component
        for (int e = tid; e < Ne; e += NTH) {
            int a, c; edge_nodes(e, a, c);
            int ra = par[a], rb = par[c];
            if (ra != rb) {
                unsigned long long wb = (unsigned long long)__double_as_longlong(ew[e]);
                atomicMin(&cbW[ra], wb); atomicMin(&cbW[rb], wb);
            }
        }
        __syncthreads();
        // pass 2: min edge index among exact-min-weight edges (stable-sort tie-break)
        for (int e = tid; e < Ne; e += NTH) {
            int a, c; edge_nodes(e, a, c);
            int ra = par[a], rb = par[c];
            if (ra != rb) {
                unsigned long long wb = (unsigned long long)__double_as_longlong(ew[e]);
                if (wb == cbW[ra]) atomicMin(&cbE[ra], e);
                if (wb == cbW[rb]) atomicMin(&cbE[rb], e);
            }
        }
        __syncthreads();
        // select + mark + build adjacency
        for (int r = tid; r < Nn; r += NTH) {
            if (par[r] == r) {
                int e = cbE[r];
                if (e != 0x7fffffff) {
                    int a, c; edge_nodes(e, a, c);
                    int ra = par[a], rb = par[c];
                    nxt[r] = (ra == r) ? rb : ra;
                    if (atomicExch(&mstf[e], 1) == 0) {
                        atomicAdd(&sMst, 1);
                        int pa = atomicAdd(&deg[a], 1); adjN[a * 4 + pa] = c; adjE[a * 4 + pa] = e;
                        int pb = atomicAdd(&deg[c], 1); adjN[c * 4 + pb] = a; adjE[c * 4 + pb] = e;
                    }
                } else nxt[r] = r;
            }
        }
        __syncthreads();
        // break 2-cycles (mutual pairs share the same edge under distinct total order)
        for (int r = tid; r < Nn; r += NTH) {
            if (par[r] == r) {
                int o = nxt[r];
                if (o != r && nxt[o] == r && r < o) nxt[r] = r;
            }
        }
        __syncthreads();
        // pointer jumping until stable
        while (true) {
            if (tid == 0) sChg = 0;
            __syncthreads();
            for (int r = tid; r < Nn; r += NTH) {
                if (par[r] == r) {
                    int nr = nxt[r], nnr = nxt[nr];
                    if (nr != nnr) { nxt[r] = nnr; sChg = 1; }
                }
            }
            __syncthreads();
            if (!sChg) break;
        }
        for (int r = tid; r < Nn; r += NTH)
            if (par[r] == r) uf[r] = nxt[r];
        __syncthreads();
    }

    // ---- BFS from node 0 (level-synchronous); compute filter weights ----
    if (tid == 0) { par[0] = 0; ord[0] = 0; wgt[0] = 0.0f; lev[0] = 0; lev[1] = 1; }
    __syncthreads();
    int cs = 0, ce = 1, D = 1;
    for (int guard = 0; guard < Nn && ce < Nn; guard++) {
        if (tid == 0) sNxt = 0;
        __syncthreads();
        for (int i = cs + tid; i < ce; i += NTH) {
            int u = ord[i], pu = par[u], dg = deg[u];
            for (int k = 0; k < dg; k++) {
                int v = adjN[u * 4 + k];
                if (v != pu) {
                    int pos = ce + atomicAdd(&sNxt, 1);
                    ord[pos] = v; par[v] = u;
                    wgt[v] = expf(-(float)ew[adjE[u * 4 + k]] / sigma);
                }
            }
        }
        __syncthreads();
        cs = ce; ce += sNxt; D++;
        if (tid == 0) lev[D] = ce;
        __syncthreads();
    }

    // ---- DP up: children before parents (scatter-add == jax .at[].add) ----
    for (int d = D - 1; d >= 1; d--) {
        int s0 = lev[d], s1 = lev[d + 1];
        for (int i = s0 + tid; i < s1; i += NTH) {
            int u = ord[i]; float w = wgt[u]; int p = par[u];
            #pragma unroll
            for (int c = 0; c <= Cc; c++)
                atomicAdd(&A[c * Nn + p], w * A[c * Nn + u]);
        }
        __syncthreads();
    }
    // ---- DP down: parents before children, in place ----
    for (int d = 1; d < D; d++) {
        int s0 = lev[d], s1 = lev[d + 1];
        for (int i = s0 + tid; i < s1; i += NTH) {
            int u = ord[i]; float w = wgt[u]; int p = par[u];
            #pragma unroll
            for (int c = 0; c <= Cc; c++) {
                float au = A[c * Nn + u];
                A[c * Nn + u] = au + w * (A[c * Nn + p] - w * au);
            }
        }
        __syncthreads();
    }

    // ---- epilogue ----
    if (mode == 0) {
        // normalize in place; reset norm channel for the next filter
        for (int t = tid; t < Cc * Nn; t += NTH) {
            int c = t / Nn, n = t - c * Nn;
            A[c * Nn + n] = A[c * Nn + n] / A[Cc * Nn + n];
        }
        __syncthreads();
        for (int n = tid; n < Nn; n += NTH) A[Cc * Nn + n] = 1.0f;
    } else {
        double ls = 0.0, cnt = 0.0;
        for (int t = tid; t < Cc * Nn; t += NTH) {
            int c = t / Nn, n = t - c * Nn;
            int h = n / Ww, w2 = n - h * Ww;
            float r = roi[(size_t)b * (2 * Hh) * (2 * Ww) + (size_t)(2 * h) * (2 * Ww) + 2 * w2];
            float as = A[c * Nn + n] / A[Cc * Nn + n];
            float pp = prob[((size_t)b * Cc + c) * Nn + n];
            ls += (double)(r * fabsf(pp - as));
            if (c == 0) cnt += (double)r;
        }
        __shared__ double sl[NTH], sc2[NTH];
        sl[tid] = ls; sc2[tid] = cnt;
        __syncthreads();
        for (int s = NTH / 2; s > 0; s >>= 1) {
            if (tid < s) { sl[tid] += sl[tid + s]; sc2[tid] += sc2[tid + s]; }
            __syncthreads();
        }
        if (tid == 0) { atomicAdd(acc, sl[0]); atomicAdd(acc + 1, sc2[0]); }
    }
}

__global__ void k_final(const double* __restrict__ acc, float* __restrict__ out) {
    if (blockIdx.x == 0 && threadIdx.x == 0)
        out[0] = (acc[1] > 0.0) ? (float)(acc[0] / acc[1]) : 0.0f;
}

extern "C" void kernel_launch(void* const* d_in, const int* in_sizes, int n_in,
                              void* d_out, int out_size, void* d_ws, size_t ws_size,
                              hipStream_t stream) {
    const float* preds = (const float*)d_in[0];
    const float* lowf  = (const float*)d_in[1];
    const float* highf = (const float*)d_in[2];
    const float* roi   = (const float*)d_in[3];
    char* ws = (char*)d_ws;
    float* out = (float*)d_out;
    double* ewl = (double*)(ws + OFF_EWL);
    double* ewh = (double*)(ws + OFF_EWH);

    int totalI = Bn * (Cc + 1) * Nn;
    k_init<<<(totalI + 255) / 256, 256, 0, stream>>>(
        preds, (float*)(ws + OFF_PROB), (float*)(ws + OFF_A), (double*)(ws + OFF_ACC));
    k_edgew<<<(Bn * Ne + 255) / 256, 256, 0, stream>>>(lowf, Clow, ewl);
    k_tree<<<Bn, NTH, 0, stream>>>(ws, ewl, 0.02f, 0, nullptr);
    k_edgew<<<(Bn * Ne + 255) / 256, 256, 0, stream>>>(highf, Chigh, ewh);
    k_tree<<<Bn, NTH, 0, stream>>>(ws, ewh, 1.0f, 1, roi);
    k_final<<<1, 64, 0, stream>>>((const double*)(ws + OFF_ACC), out);
}

// Round 2
// 2449.215 us; speedup vs baseline: 6.8375x; 6.8375x over previous
//
#include <hip/hip_runtime.h>
#include <math.h>
#include <stdint.h>
#include <stddef.h>

// TreeEnergyLoss on gfx950 — R2: phase-split, LDS-resident tree work.
//
//  * k_mst  <<<8,1024>>> : Boruvka per (tree,batch); uf/comp/nxt as ushort in LDS.
//  * k_bfs  <<<8,256>>>  : BFS from node 0; emits level-compacted topology
//                          (ord, parPos, wgt indexed by BFS position).
//  * k_dp   <<<88,256>>> : per (batch,channel) two-pass DP entirely in LDS.
//  * MST matches host Kruskal: exact float64 weights, stable tie-break
//    (two-pass component-min: weight bits, then edge index).
//  * Tree filter is root/orientation independent => root at node 0 is fine.

namespace {
constexpr int Bn  = 4, Cc = 21, Hh = 96, Ww = 96;
constexpr int Nn  = Hh * Ww;              // 9216 nodes
constexpr int EhE = Hh * (Ww - 1);        // 9120 horizontal edges
constexpr int Ne  = EhE + (Hh - 1) * Ww;  // 18240 edges
constexpr int Clow = 3, Chigh = 512;
constexpr int NCh = Cc + 1;               // 22 channels incl. norm
constexpr int MAXD = 2048;                // max BFS depth (grid MST depth ~few hundred)

// workspace layout (bytes)
constexpr size_t OFF_ACC  = 0;                                       // 2 doubles
constexpr size_t OFF_PROB = 256;                                     // float[B][21][Nn]
constexpr size_t OFF_S1   = OFF_PROB + (size_t)Bn * Cc * Nn * 4;     // float[B][22][Nn]
constexpr size_t OFF_S2   = OFF_S1   + (size_t)Bn * NCh * Nn * 4;    // float[B][22][Nn]
constexpr size_t OFF_EW   = OFF_S2   + (size_t)Bn * NCh * Nn * 4;    // double[2][B][Ne]
constexpr size_t OFF_ORD  = OFF_EW   + (size_t)2 * Bn * Ne * 8;      // int[8][Nn]
constexpr size_t OFF_PPOS = OFF_ORD  + (size_t)8 * Nn * 4;           // int[8][Nn]
constexpr size_t OFF_WGT  = OFF_PPOS + (size_t)8 * Nn * 4;           // float[8][Nn]
constexpr size_t OFF_LEV  = OFF_WGT  + (size_t)8 * Nn * 4;           // int[8][MAXD]
constexpr size_t OFF_D    = OFF_LEV  + (size_t)8 * MAXD * 4;         // int[8]
constexpr size_t OFF_CBW  = OFF_D    + 256;                          // ull[8][Nn]
constexpr size_t OFF_CBE  = OFF_CBW  + (size_t)8 * Nn * 8;           // int[8][Nn]
constexpr size_t OFF_DEG  = OFF_CBE  + (size_t)8 * Nn * 4;           // int[8][Nn]
constexpr size_t OFF_ADJN = OFF_DEG  + (size_t)8 * Nn * 4;           // int[8][Nn*4]
constexpr size_t OFF_ADJE = OFF_ADJN + (size_t)8 * Nn * 16;          // int[8][Nn*4]
constexpr size_t OFF_MSTF = OFF_ADJE + (size_t)8 * Nn * 16;          // int[8][Ne]
} // namespace

// edge id -> endpoints, matching reference concatenate([eh, ev]) ordering
__device__ __forceinline__ void edge_nodes(int e, int& a, int& b) {
    if (e < EhE) {                    // horizontal
        int h = e / (Ww - 1), w = e - h * (Ww - 1);
        a = h * Ww + w; b = a + 1;
    } else {                          // vertical
        int e2 = e - EhE;
        int h = e2 / Ww, w = e2 - h * Ww;
        a = h * Ww + w; b = a + Ww;
    }
}

__device__ __forceinline__ int uf_find16(unsigned short* uf, int x) {
    while (true) {
        int p = uf[x];
        if (p == x) return x;
        int gp = uf[p];
        if (gp != p) uf[x] = (unsigned short)gp;  // path halving (benign races)
        x = gp;
    }
}

__global__ void k_init(const float* __restrict__ preds, float* __restrict__ prob,
                       double* __restrict__ acc) {
    int idx = blockIdx.x * blockDim.x + threadIdx.x;
    if (idx == 0) { acc[0] = 0.0; acc[1] = 0.0; }
    if (idx >= Bn * Cc * Nn) return;
    float x = preds[idx];
    prob[idx] = 1.0f / (1.0f + expf(-x));
}

// exact float64 edge weights: sequential channel sum matches numpy axis-0 reduce
__global__ void k_edgew(const float* __restrict__ feat, int C, double* __restrict__ ew) {
    int idx = blockIdx.x * blockDim.x + threadIdx.x;
    if (idx >= Bn * Ne) return;
    int b = idx / Ne, e = idx - b * Ne;
    int a, c2; edge_nodes(e, a, c2);
    const float* f = feat + (size_t)b * C * Nn;
    double s = 0.0;
    for (int c = 0; c < C; c++) {
        double d = (double)f[(size_t)c * Nn + a] - (double)f[(size_t)c * Nn + c2];
        s += d * d;
    }
    ew[idx] = s;
}

// Boruvka MST. One block per (tree,batch) slot tb in [0,8).
__global__ void __launch_bounds__(1024)
k_mst(char* __restrict__ ws) {
    const int tb = blockIdx.x, tid = threadIdx.x;
    const double* ew = (const double*)(ws + OFF_EW) + (size_t)tb * Ne;
    unsigned long long* cbW = (unsigned long long*)(ws + OFF_CBW) + (size_t)tb * Nn;
    int* cbE  = (int*)(ws + OFF_CBE)  + (size_t)tb * Nn;
    int* deg  = (int*)(ws + OFF_DEG)  + (size_t)tb * Nn;
    int* adjN = (int*)(ws + OFF_ADJN) + (size_t)tb * Nn * 4;
    int* adjE = (int*)(ws + OFF_ADJE) + (size_t)tb * Nn * 4;
    int* mstf = (int*)(ws + OFF_MSTF) + (size_t)tb * Ne;

    __shared__ unsigned short uf[Nn], comp[Nn], nxt[Nn];
    __shared__ int sMst, sChg;

    if (tid == 0) sMst = 0;
    for (int i = tid; i < Nn; i += 1024) { uf[i] = (unsigned short)i; deg[i] = 0; }
    for (int e = tid; e < Ne; e += 1024) mstf[e] = 0;
    __syncthreads();

    for (int round = 0; round < 24; round++) {
        if (sMst >= Nn - 1) break;
        for (int i = tid; i < Nn; i += 1024) { cbW[i] = ~0ull; cbE[i] = 0x7fffffff; }
        for (int i = tid; i < Nn; i += 1024) comp[i] = (unsigned short)uf_find16(uf, i);
        __syncthreads();
        // pass 1: min weight bits per component
        for (int e = tid; e < Ne; e += 1024) {
            int a, c; edge_nodes(e, a, c);
            int ra = comp[a], rb = comp[c];
            if (ra != rb) {
                unsigned long long wb = (unsigned long long)__double_as_longlong(ew[e]);
                atomicMin(&cbW[ra], wb); atomicMin(&cbW[rb], wb);
            }
        }
        __syncthreads();
        // pass 2: min edge index among exact-min-weight edges (stable tie-break)
        for (int e = tid; e < Ne; e += 1024) {
            int a, c; edge_nodes(e, a, c);
            int ra = comp[a], rb = comp[c];
            if (ra != rb) {
                unsigned long long wb = (unsigned long long)__double_as_longlong(ew[e]);
                if (wb == cbW[ra]) atomicMin(&cbE[ra], e);
                if (wb == cbW[rb]) atomicMin(&cbE[rb], e);
            }
        }
        __syncthreads();
        // select + mark + adjacency
        for (int r = tid; r < Nn; r += 1024) {
            if (comp[r] == r) {
                int e = cbE[r];
                if (e != 0x7fffffff) {
                    int a, c; edge_nodes(e, a, c);
                    int ra = comp[a], rb = comp[c];
                    nxt[r] = (unsigned short)((ra == r) ? rb : ra);
                    if (atomicExch(&mstf[e], 1) == 0) {
                        atomicAdd(&sMst, 1);
                        int pa = atomicAdd(&deg[a], 1); adjN[a * 4 + pa] = c; adjE[a * 4 + pa] = e;
                        int pb = atomicAdd(&deg[c], 1); adjN[c * 4 + pb] = a; adjE[c * 4 + pb] = e;
                    }
                } else nxt[r] = (unsigned short)r;
            }
        }
        __syncthreads();
        // break 2-cycles
        for (int r = tid; r < Nn; r += 1024) {
            if (comp[r] == r) {
                int o = nxt[r];
                if (o != r && nxt[o] == r && r < o) nxt[r] = (unsigned short)r;
            }
        }
        __syncthreads();
        // pointer jumping (LDS only)
        while (true) {
            if (tid == 0) sChg = 0;
            __syncthreads();
            for (int r = tid; r < Nn; r += 1024) {
                if (comp[r] == r) {
                    int nr = nxt[r], nnr = nxt[nr];
                    if (nr != nnr) { nxt[r] = (unsigned short)nnr; sChg = 1; }
                }
            }
            __syncthreads();
            if (!sChg) break;
        }
        for (int r = tid; r < Nn; r += 1024)
            if (comp[r] == r) uf[r] = nxt[r];
        __syncthreads();
    }
}

// BFS from node 0; emit level-compacted topology. One block per tb.
__global__ void __launch_bounds__(256)
k_bfs(char* __restrict__ ws) {
    const int tb = blockIdx.x, tid = threadIdx.x;
    const int tree = tb >> 2;
    const double* ew = (const double*)(ws + OFF_EW) + (size_t)tb * Ne;
    const int* deg  = (const int*)(ws + OFF_DEG)  + (size_t)tb * Nn;
    const int* adjN = (const int*)(ws + OFF_ADJN) + (size_t)tb * Nn * 4;
    const int* adjE = (const int*)(ws + OFF_ADJE) + (size_t)tb * Nn * 4;
    int*   ordG  = (int*)(ws + OFF_ORD)  + (size_t)tb * Nn;
    int*   pposG = (int*)(ws + OFF_PPOS) + (size_t)tb * Nn;
    float* wgtG  = (float*)(ws + OFF_WGT) + (size_t)tb * Nn;
    int*   levG  = (int*)(ws + OFF_LEV)  + (size_t)tb * MAXD;
    int*   dG    = (int*)(ws + OFF_D);
    const float inv_sigma = tree ? 1.0f : 50.0f;  // 1/0.02 for low tree

    __shared__ unsigned short ordS[Nn], parNode[Nn], pposS[Nn];
    __shared__ int levS[MAXD];
    __shared__ int sNxt;

    if (tid == 0) {
        ordS[0] = 0; parNode[0] = 0xFFFF; pposS[0] = 0;
        levS[0] = 0; levS[1] = 1; wgtG[0] = 0.0f;
    }
    __syncthreads();
    int cs = 0, ce = 1, D = 1;
    for (int guard = 0; guard < Nn && ce < Nn; guard++) {
        if (tid == 0) sNxt = 0;
        __syncthreads();
        for (int i = cs + tid; i < ce; i += 256) {
            int u = ordS[i], pu = parNode[u];
            int dgu = deg[u];
            for (int k = 0; k < dgu; k++) {
                int v = adjN[u * 4 + k];
                if (v != pu) {
                    int pos = ce + atomicAdd(&sNxt, 1);
                    ordS[pos] = (unsigned short)v;
                    parNode[v] = (unsigned short)u;
                    pposS[pos] = (unsigned short)i;
                    wgtG[pos] = expf(-(float)ew[adjE[u * 4 + k]] * inv_sigma);
                }
            }
        }
        __syncthreads();
        cs = ce; ce += sNxt; D++;
        if (tid == 0) levS[D] = ce;
        __syncthreads();
    }
    if (tid == 0) dG[tb] = D;
    for (int i = tid; i < Nn; i += 256) { ordG[i] = ordS[i]; pposG[i] = pposS[i]; }
    for (int d = tid; d <= D; d += 256) levG[d] = levS[d];
}

// Two-pass tree DP for one (batch, channel), entirely in LDS.
// inMode 0: input = sigmoid prob (norm channel = 1)
// inMode 1: input = S1[c]/S1[21]  (norm channel = 1)
__global__ void __launch_bounds__(256)
k_dp(char* __restrict__ ws, int tree, int inMode) {
    const int bc = blockIdx.x;
    const int b = bc / NCh, c = bc % NCh;
    const int tb = tree * Bn + b;
    const int tid = threadIdx.x;
    const int*   ordG  = (const int*)(ws + OFF_ORD)  + (size_t)tb * Nn;
    const int*   pposG = (const int*)(ws + OFF_PPOS) + (size_t)tb * Nn;
    const float* wgtG  = (const float*)(ws + OFF_WGT) + (size_t)tb * Nn;
    const int*   levG  = (const int*)(ws + OFF_LEV)  + (size_t)tb * MAXD;
    const int D = ((const int*)(ws + OFF_D))[tb];
    const float* prob = (const float*)(ws + OFF_PROB);
    const float* S1   = (const float*)(ws + OFF_S1);
    float* Sout = (float*)(ws + (tree ? OFF_S2 : OFF_S1));

    __shared__ float Al[Nn];
    __shared__ unsigned short pposS[Nn];
    __shared__ int levS[MAXD];

    for (int i = tid; i < Nn; i += 256) {
        int node = ordG[i];
        float v;
        if (c == Cc) v = 1.0f;
        else if (inMode == 0) v = prob[((size_t)b * Cc + c) * Nn + node];
        else v = S1[((size_t)b * NCh + c) * Nn + node] /
                 S1[((size_t)b * NCh + Cc) * Nn + node];
        Al[i] = v;
        pposS[i] = (unsigned short)pposG[i];
    }
    for (int d = tid; d <= D; d += 256) levS[d] = levG[d];
    __syncthreads();

    // up: children before parents (scatter-add == jax .at[].add)
    for (int d = D - 1; d >= 1; d--) {
        int s0 = levS[d], s1 = levS[d + 1];
        for (int i = s0 + tid; i < s1; i += 256)
            atomicAdd(&Al[pposS[i]], wgtG[i] * Al[i]);
        __syncthreads();
    }
    // down: parents before children
    for (int d = 1; d < D; d++) {
        int s0 = levS[d], s1 = levS[d + 1];
        for (int i = s0 + tid; i < s1; i += 256) {
            float w = wgtG[i], a = Al[i];
            Al[i] = a + w * (Al[pposS[i]] - w * a);
        }
        __syncthreads();
    }
    // scatter back to node order
    for (int i = tid; i < Nn; i += 256)
        Sout[((size_t)b * NCh + c) * Nn + ordG[i]] = Al[i];
}

__global__ void k_loss(char* __restrict__ ws, const float* __restrict__ roi) {
    const int tid = threadIdx.x;
    int idx = blockIdx.x * 256 + tid;
    const float* prob = (const float*)(ws + OFF_PROB);
    const float* S2   = (const float*)(ws + OFF_S2);
    double* acc = (double*)(ws + OFF_ACC);
    double ls = 0.0, cnt = 0.0;
    if (idx < Bn * Cc * Nn) {
        int b = idx / (Cc * Nn);
        int rem = idx - b * (Cc * Nn);
        int c = rem / Nn, n = rem - c * Nn;
        int h = n / Ww, w2 = n - h * Ww;
        float r = roi[(size_t)b * (2 * Hh) * (2 * Ww) + (size_t)(2 * h) * (2 * Ww) + 2 * w2];
        float as = S2[((size_t)b * NCh + c) * Nn + n] / S2[((size_t)b * NCh + Cc) * Nn + n];
        float pp = prob[((size_t)b * Cc + c) * Nn + n];
        ls = (double)(r * fabsf(pp - as));
        if (c == 0) cnt = (double)r;
    }
    __shared__ double sl[256], sc2[256];
    sl[tid] = ls; sc2[tid] = cnt;
    __syncthreads();
    for (int s = 128; s > 0; s >>= 1) {
        if (tid < s) { sl[tid] += sl[tid + s]; sc2[tid] += sc2[tid + s]; }
        __syncthreads();
    }
    if (tid == 0) { atomicAdd(acc, sl[0]); atomicAdd(acc + 1, sc2[0]); }
}

__global__ void k_final(const double* __restrict__ acc, float* __restrict__ out) {
    if (blockIdx.x == 0 && threadIdx.x == 0)
        out[0] = (acc[1] > 0.0) ? (float)(acc[0] / acc[1]) : 0.0f;
}

extern "C" void kernel_launch(void* const* d_in, const int* in_sizes, int n_in,
                              void* d_out, int out_size, void* d_ws, size_t ws_size,
                              hipStream_t stream) {
    const float* preds = (const float*)d_in[0];
    const float* lowf  = (const float*)d_in[1];
    const float* highf = (const float*)d_in[2];
    const float* roi   = (const float*)d_in[3];
    char* ws = (char*)d_ws;
    float* out = (float*)d_out;
    double* ewl = (double*)(ws + OFF_EW);                        // trees 0: tb 0..3
    double* ewh = (double*)(ws + OFF_EW) + (size_t)Bn * Ne;      // tree 1: tb 4..7

    k_init<<<(Bn * Cc * Nn + 255) / 256, 256, 0, stream>>>(
        preds, (float*)(ws + OFF_PROB), (double*)(ws + OFF_ACC));
    k_edgew<<<(Bn * Ne + 255) / 256, 256, 0, stream>>>(lowf, Clow, ewl);
    k_edgew<<<(Bn * Ne + 255) / 256, 256, 0, stream>>>(highf, Chigh, ewh);
    k_mst<<<8, 1024, 0, stream>>>(ws);
    k_bfs<<<8, 256, 0, stream>>>(ws);
    k_dp<<<Bn * NCh, 256, 0, stream>>>(ws, 0, 0);
    k_dp<<<Bn * NCh, 256, 0, stream>>>(ws, 1, 1);
    k_loss<<<(Bn * Cc * Nn + 255) / 256, 256, 0, stream>>>(ws, roi);
    k_final<<<1, 64, 0, stream>>>((const double*)(ws + OFF_ACC), out);
}

// Round 3
// 1566.278 us; speedup vs baseline: 10.6919x; 1.5637x over previous
//
#include <hip/hip_runtime.h>
#include <math.h>
#include <stdint.h>
#include <stddef.h>

// TreeEnergyLoss on gfx950 — R3: LDS-resident BFS via grid-direction masks.
//
//  * Tree adjacency = 4-bit dir mask per node (E,W,S,N) -> whole BFS fits in
//    64KB LDS; level loop touches no global memory (2 barriers + LDS chain).
//  * Edge weights / topology outputs resolved in a flat post-pass.
//  * MST matches host Kruskal: exact float64 weights, stable tie-break.
//  * Filter is root/orientation independent => root at node 0.

namespace {
constexpr int Bn  = 4, Cc = 21, Hh = 96, Ww = 96;
constexpr int Nn  = Hh * Ww;              // 9216
constexpr int EhE = Hh * (Ww - 1);        // 9120
constexpr int Ne  = EhE + (Hh - 1) * Ww;  // 18240
constexpr int Clow = 3, Chigh = 512;
constexpr int NCh = Cc + 1;               // 22
constexpr int MAXD = 2048;

// workspace layout (bytes)
constexpr size_t OFF_ACC  = 0;                                        // 2 doubles
constexpr size_t OFF_PROB = 256;                                      // float[B][21][Nn]
constexpr size_t OFF_S1   = OFF_PROB + (size_t)Bn * Cc * Nn * 4;      // float[B][22][Nn]
constexpr size_t OFF_S2   = OFF_S1   + (size_t)Bn * NCh * Nn * 4;     // float[B][22][Nn]
constexpr size_t OFF_EW   = OFF_S2   + (size_t)Bn * NCh * Nn * 4;     // double[8][Ne]
constexpr size_t OFF_ORD  = OFF_EW   + (size_t)8 * Ne * 8;            // int[8][Nn]
constexpr size_t OFF_TOPO = OFF_ORD  + (size_t)8 * Nn * 4;            // uint2[8][Nn] {wgt,ppos}
constexpr size_t OFF_LEV  = OFF_TOPO + (size_t)8 * Nn * 8;            // int[8][MAXD]
constexpr size_t OFF_D    = OFF_LEV  + (size_t)8 * MAXD * 4;          // int[8]
constexpr size_t OFF_DIR  = OFF_D    + 256;                           // int[8][Nn] dir mask
constexpr size_t OFF_MSTF = OFF_DIR  + (size_t)8 * Nn * 4;            // int[8][Ne]
constexpr size_t OFF_CBW  = OFF_MSTF + (size_t)8 * Ne * 4;            // ull[8][Nn]
constexpr size_t OFF_CBE  = OFF_CBW  + (size_t)8 * Nn * 8;            // int[8][Nn]
} // namespace

// edge id -> endpoints, matching reference concatenate([eh, ev]) ordering
__device__ __forceinline__ void edge_nodes(int e, int& a, int& b) {
    if (e < EhE) { int h = e / (Ww - 1), w = e - h * (Ww - 1); a = h * Ww + w; b = a + 1; }
    else { int e2 = e - EhE; int h = e2 / Ww, w = e2 - h * Ww; a = h * Ww + w; b = a + Ww; }
}
// dirs: 0=E(+1) 1=W(-1) 2=S(+96) 3=N(-96); rev(d)=d^1
__device__ __forceinline__ int dir_delta(int d) {
    return (d == 0) ? 1 : (d == 1) ? -1 : (d == 2) ? Ww : -Ww;
}
__device__ __forceinline__ int edge_of(int u, int d) {
    int h = u / Ww, w = u - h * Ww;
    if (d == 0) return h * (Ww - 1) + w;
    if (d == 1) return h * (Ww - 1) + w - 1;
    if (d == 2) return EhE + u;
    return EhE + u - Ww;
}

__device__ __forceinline__ int uf_find16(unsigned short* uf, int x) {
    while (true) {
        int p = uf[x];
        if (p == x) return x;
        int gp = uf[p];
        if (gp != p) uf[x] = (unsigned short)gp;  // path halving (benign races)
        x = gp;
    }
}

__global__ void k_init(const float* __restrict__ preds, float* __restrict__ prob,
                       double* __restrict__ acc) {
    int idx = blockIdx.x * blockDim.x + threadIdx.x;
    if (idx == 0) { acc[0] = 0.0; acc[1] = 0.0; }
    if (idx >= Bn * Cc * Nn) return;
    prob[idx] = 1.0f / (1.0f + expf(-preds[idx]));
}

// exact float64 edge weights: sequential channel sum matches numpy axis-0 reduce
__global__ void k_edgew(const float* __restrict__ feat, int C, double* __restrict__ ew) {
    int idx = blockIdx.x * blockDim.x + threadIdx.x;
    if (idx >= Bn * Ne) return;
    int b = idx / Ne, e = idx - b * Ne;
    int a, c2; edge_nodes(e, a, c2);
    const float* f = feat + (size_t)b * C * Nn;
    double s = 0.0;
    for (int c = 0; c < C; c++) {
        double d = (double)f[(size_t)c * Nn + a] - (double)f[(size_t)c * Nn + c2];
        s += d * d;
    }
    ew[idx] = s;
}

// Boruvka MST; emits per-node dir bitmask. One block per (tree,batch) tb.
__global__ void __launch_bounds__(1024)
k_mst(char* __restrict__ ws) {
    const int tb = blockIdx.x, tid = threadIdx.x;
    const double* ew = (const double*)(ws + OFF_EW) + (size_t)tb * Ne;
    unsigned long long* cbW = (unsigned long long*)(ws + OFF_CBW) + (size_t)tb * Nn;
    int* cbE  = (int*)(ws + OFF_CBE)  + (size_t)tb * Nn;
    int* dirG = (int*)(ws + OFF_DIR)  + (size_t)tb * Nn;
    int* mstf = (int*)(ws + OFF_MSTF) + (size_t)tb * Ne;

    __shared__ unsigned short uf[Nn], comp[Nn], nxt[Nn];
    __shared__ int sMst, sChg;

    if (tid == 0) sMst = 0;
    for (int i = tid; i < Nn; i += 1024) { uf[i] = (unsigned short)i; dirG[i] = 0; }
    for (int e = tid; e < Ne; e += 1024) mstf[e] = 0;
    __syncthreads();

    for (int round = 0; round < 24; round++) {
        if (sMst >= Nn - 1) break;
        for (int i = tid; i < Nn; i += 1024) { cbW[i] = ~0ull; cbE[i] = 0x7fffffff; }
        for (int i = tid; i < Nn; i += 1024) comp[i] = (unsigned short)uf_find16(uf, i);
        __syncthreads();
        // pass 1: min weight bits per component
        for (int e = tid; e < Ne; e += 1024) {
            int a, c; edge_nodes(e, a, c);
            int ra = comp[a], rb = comp[c];
            if (ra != rb) {
                unsigned long long wb = (unsigned long long)__double_as_longlong(ew[e]);
                atomicMin(&cbW[ra], wb); atomicMin(&cbW[rb], wb);
            }
        }
        __syncthreads();
        // pass 2: min edge index among exact-min-weight edges (stable tie-break)
        for (int e = tid; e < Ne; e += 1024) {
            int a, c; edge_nodes(e, a, c);
            int ra = comp[a], rb = comp[c];
            if (ra != rb) {
                unsigned long long wb = (unsigned long long)__double_as_longlong(ew[e]);
                if (wb == cbW[ra]) atomicMin(&cbE[ra], e);
                if (wb == cbW[rb]) atomicMin(&cbE[rb], e);
            }
        }
        __syncthreads();
        // select + mark + dir bitmask
        for (int r = tid; r < Nn; r += 1024) {
            if (comp[r] == r) {
                int e = cbE[r];
                if (e != 0x7fffffff) {
                    int a, c; edge_nodes(e, a, c);
                    int ra = comp[a], rb = comp[c];
                    nxt[r] = (unsigned short)((ra == r) ? rb : ra);
                    if (atomicExch(&mstf[e], 1) == 0) {
                        atomicAdd(&sMst, 1);
                        int da = (c == a + 1) ? 0 : 2;           // E or S from a
                        atomicOr(&dirG[a], 1 << da);
                        atomicOr(&dirG[c], 1 << (da ^ 1));       // W or N from c
                    }
                } else nxt[r] = (unsigned short)r;
            }
        }
        __syncthreads();
        // break 2-cycles
        for (int r = tid; r < Nn; r += 1024) {
            if (comp[r] == r) {
                int o = nxt[r];
                if (o != r && nxt[o] == r && r < o) nxt[r] = (unsigned short)r;
            }
        }
        __syncthreads();
        // pointer jumping (LDS only)
        while (true) {
            if (tid == 0) sChg = 0;
            __syncthreads();
            for (int r = tid; r < Nn; r += 1024) {
                if (comp[r] == r) {
                    int nr = nxt[r], nnr = nxt[nr];
                    if (nr != nnr) { nxt[r] = (unsigned short)nnr; sChg = 1; }
                }
            }
            __syncthreads();
            if (!sChg) break;
        }
        for (int r = tid; r < Nn; r += 1024)
            if (comp[r] == r) uf[r] = nxt[r];
        __syncthreads();
    }
}

// LDS-resident BFS from node 0; flat post-pass emits ord/topo/lev.
__global__ void __launch_bounds__(256)
k_bfs(char* __restrict__ ws) {
    const int tb = blockIdx.x, tid = threadIdx.x;
    const int tree = tb >> 2;
    const double* ew = (const double*)(ws + OFF_EW) + (size_t)tb * Ne;
    const int* dirG = (const int*)(ws + OFF_DIR) + (size_t)tb * Nn;
    int*   ordG  = (int*)(ws + OFF_ORD)  + (size_t)tb * Nn;
    uint2* topoG = (uint2*)(ws + OFF_TOPO) + (size_t)tb * Nn;
    int*   levG  = (int*)(ws + OFF_LEV)  + (size_t)tb * MAXD;
    int*   dG    = (int*)(ws + OFF_D);
    const float inv_sigma = tree ? 1.0f : 50.0f;

    __shared__ unsigned short ordS[Nn], posOf[Nn];
    __shared__ unsigned char dirS[Nn], parS[Nn];
    __shared__ unsigned short levS[MAXD];
    __shared__ int sCum;

    for (int i = tid; i < Nn; i += 256) dirS[i] = (unsigned char)dirG[i];
    if (tid == 0) {
        sCum = 0; ordS[0] = 0; parS[0] = 0xFE;
        levS[0] = 0; levS[1] = 1;
    }
    __syncthreads();

    int cs = 0, ce = 1, D = 1;
    for (int guard = 0; guard < Nn && ce < Nn && D < MAXD - 1; guard++) {
        for (int i = cs + tid; i < ce; i += 256) {
            int u = ordS[i], m = dirS[u], pd = parS[u];
            #pragma unroll
            for (int d = 0; d < 4; d++) {
                if (((m >> d) & 1) && d != pd) {
                    int v = u + dir_delta(d);
                    int pos = 1 + atomicAdd(&sCum, 1);
                    ordS[pos] = (unsigned short)v;
                    parS[v] = (unsigned char)(d ^ 1);
                }
            }
        }
        __syncthreads();                       // expansion writes visible
        int newCe = 1 + sCum;
        D++;
        if (tid == 0) levS[D] = (unsigned short)newCe;
        __syncthreads();                       // all read sCum before next adds
        cs = ce; ce = newCe;
    }

    // flat post-pass: inverse permutation, weights, outputs
    for (int i = tid; i < Nn; i += 256) posOf[ordS[i]] = (unsigned short)i;
    __syncthreads();
    for (int i = tid; i < Nn; i += 256) {
        int u = ordS[i];
        ordG[i] = u;
        uint2 t;
        if (i == 0) { t.x = 0u; t.y = 0u; }
        else {
            int pd = parS[u];
            int p = u + dir_delta(pd);
            int e = edge_of(u, pd);
            float w = expf(-(float)ew[e] * inv_sigma);
            t.x = __float_as_uint(w);
            t.y = (unsigned int)posOf[p];
        }
        topoG[i] = t;
    }
    if (tid == 0) dG[tb] = D;
    for (int d = tid; d <= D; d += 256) levG[d] = levS[d];
}

// Two-pass tree DP for one (batch, channel), Al in LDS.
__global__ void __launch_bounds__(128)
k_dp(char* __restrict__ ws, int tree, int inMode) {
    const int bc = blockIdx.x;
    const int b = bc / NCh, c = bc % NCh;
    const int tb = tree * Bn + b;
    const int tid = threadIdx.x;
    const int*   ordG  = (const int*)(ws + OFF_ORD)  + (size_t)tb * Nn;
    const uint2* topoG = (const uint2*)(ws + OFF_TOPO) + (size_t)tb * Nn;
    const int*   levG  = (const int*)(ws + OFF_LEV)  + (size_t)tb * MAXD;
    const int D = ((const int*)(ws + OFF_D))[tb];
    const float* prob = (const float*)(ws + OFF_PROB);
    const float* S1   = (const float*)(ws + OFF_S1);
    float* Sout = (float*)(ws + (tree ? OFF_S2 : OFF_S1));

    __shared__ float Al[Nn];
    __shared__ unsigned short pposS[Nn];
    __shared__ unsigned short levS[MAXD];

    for (int i = tid; i < Nn; i += 128) {
        pposS[i] = (unsigned short)topoG[i].y;
        int node = ordG[i];
        float v;
        if (c == Cc) v = 1.0f;
        else if (inMode == 0) v = prob[((size_t)b * Cc + c) * Nn + node];
        else v = S1[((size_t)b * NCh + c) * Nn + node] /
                 S1[((size_t)b * NCh + Cc) * Nn + node];
        Al[i] = v;
    }
    for (int d = tid; d <= D; d += 128) levS[d] = (unsigned short)levG[d];
    __syncthreads();

    // up: children before parents (scatter-add == jax .at[].add)
    for (int d = D - 1; d >= 1; d--) {
        int s0 = levS[d], s1 = levS[d + 1];
        for (int i = s0 + tid; i < s1; i += 128) {
            float w = __uint_as_float(topoG[i].x);
            atomicAdd(&Al[pposS[i]], w * Al[i]);
        }
        __syncthreads();
    }
    // down: parents before children
    for (int d = 1; d < D; d++) {
        int s0 = levS[d], s1 = levS[d + 1];
        for (int i = s0 + tid; i < s1; i += 128) {
            float w = __uint_as_float(topoG[i].x);
            float a = Al[i];
            Al[i] = a + w * (Al[pposS[i]] - w * a);
        }
        __syncthreads();
    }
    for (int i = tid; i < Nn; i += 128)
        Sout[((size_t)b * NCh + c) * Nn + ordG[i]] = Al[i];
}

__global__ void k_loss(char* __restrict__ ws, const float* __restrict__ roi) {
    const int tid = threadIdx.x;
    int idx = blockIdx.x * 256 + tid;
    const float* prob = (const float*)(ws + OFF_PROB);
    const float* S2   = (const float*)(ws + OFF_S2);
    double* acc = (double*)(ws + OFF_ACC);
    double ls = 0.0, cnt = 0.0;
    if (idx < Bn * Cc * Nn) {
        int b = idx / (Cc * Nn);
        int rem = idx - b * (Cc * Nn);
        int c = rem / Nn, n = rem - c * Nn;
        int h = n / Ww, w2 = n - h * Ww;
        float r = roi[(size_t)b * (2 * Hh) * (2 * Ww) + (size_t)(2 * h) * (2 * Ww) + 2 * w2];
        float as = S2[((size_t)b * NCh + c) * Nn + n] / S2[((size_t)b * NCh + Cc) * Nn + n];
        float pp = prob[((size_t)b * Cc + c) * Nn + n];
        ls = (double)(r * fabsf(pp - as));
        if (c == 0) cnt = (double)r;
    }
    __shared__ double sl[256], sc2[256];
    sl[tid] = ls; sc2[tid] = cnt;
    __syncthreads();
    for (int s = 128; s > 0; s >>= 1) {
        if (tid < s) { sl[tid] += sl[tid + s]; sc2[tid] += sc2[tid + s]; }
        __syncthreads();
    }
    if (tid == 0) { atomicAdd(acc, sl[0]); atomicAdd(acc + 1, sc2[0]); }
}

__global__ void k_final(const double* __restrict__ acc, float* __restrict__ out) {
    if (blockIdx.x == 0 && threadIdx.x == 0)
        out[0] = (acc[1] > 0.0) ? (float)(acc[0] / acc[1]) : 0.0f;
}

extern "C" void kernel_launch(void* const* d_in, const int* in_sizes, int n_in,
                              void* d_out, int out_size, void* d_ws, size_t ws_size,
                              hipStream_t stream) {
    const float* preds = (const float*)d_in[0];
    const float* lowf  = (const float*)d_in[1];
    const float* highf = (const float*)d_in[2];
    const float* roi   = (const float*)d_in[3];
    char* ws = (char*)d_ws;
    float* out = (float*)d_out;
    double* ewl = (double*)(ws + OFF_EW);                      // tb 0..3 (low tree)
    double* ewh = (double*)(ws + OFF_EW) + (size_t)Bn * Ne;    // tb 4..7 (high tree)

    k_init<<<(Bn * Cc * Nn + 255) / 256, 256, 0, stream>>>(
        preds, (float*)(ws + OFF_PROB), (double*)(ws + OFF_ACC));
    k_edgew<<<(Bn * Ne + 255) / 256, 256, 0, stream>>>(lowf, Clow, ewl);
    k_edgew<<<(Bn * Ne + 255) / 256, 256, 0, stream>>>(highf, Chigh, ewh);
    k_mst<<<8, 1024, 0, stream>>>(ws);
    k_bfs<<<8, 256, 0, stream>>>(ws);
    k_dp<<<Bn * NCh, 128, 0, stream>>>(ws, 0, 0);
    k_dp<<<Bn * NCh, 128, 0, stream>>>(ws, 1, 1);
    k_loss<<<(Bn * Cc * Nn + 255) / 256, 256, 0, stream>>>(ws, roi);
    k_final<<<1, 64, 0, stream>>>((const double*)(ws + OFF_ACC), out);
}